// Round 13
// baseline (402.800 us; speedup 1.0000x reference)
//
#include <hip/hip_runtime.h>
#include <hip/hip_cooperative_groups.h>
#include <math.h>

namespace cg = cooperative_groups;

#define NEG_SLOPE 0.2f

typedef __attribute__((ext_vector_type(8))) short s16x8;   // 8 bf16 (4 VGPRs)
typedef __attribute__((ext_vector_type(4))) float f32x4;
typedef unsigned short ushort_t;
typedef unsigned int uint_t;

__device__ inline ushort_t f2bf(float f) {
    unsigned u = __float_as_uint(f);
    unsigned r = (u + 0x7fff + ((u >> 16) & 1)) >> 16;   // RNE
    return (ushort_t)r;
}
__device__ inline float bf2f(ushort_t u) {
    return __uint_as_float(((unsigned)u) << 16);
}

// ---------------- fused fp32 -> bf16 conversion for two arrays ----------------
__global__ __launch_bounds__(256) void cvt2_kernel(const float* __restrict__ a,
        ushort_t* __restrict__ oa, int na4,
        const float* __restrict__ b, ushort_t* __restrict__ ob, int nb4) {
    int i = blockIdx.x * 256 + threadIdx.x;
    if (i < na4) {
        float4 v = ((const float4*)a)[i];
        ushort4 o;
        o.x = f2bf(v.x); o.y = f2bf(v.y); o.z = f2bf(v.z); o.w = f2bf(v.w);
        ((ushort4*)oa)[i] = o;
    } else if (i - na4 < nb4) {
        int k = i - na4;
        float4 v = ((const float4*)b)[k];
        ushort4 o;
        o.x = f2bf(v.x); o.y = f2bf(v.y); o.z = f2bf(v.z); o.w = f2bf(v.w);
        ((ushort4*)ob)[k] = o;
    }
}

// ---------------- cooperative CSR build: zero+hist+scan+scatter in ONE kernel ----------------
// grid = NT blocks x 1024 threads, NT = ceil(n/1024) (<= 64)
__global__ __launch_bounds__(1024) void csr_coop(const int* __restrict__ ei,
        int* __restrict__ deg, int* __restrict__ rowptr, int* __restrict__ cursor,
        int* __restrict__ adj, int* __restrict__ bsum, int E, int n) {
    cg::grid_group grid = cg::this_grid();
    const int t = threadIdx.x, b = blockIdx.x;
    const int gt = b * 1024 + t, GT = gridDim.x * 1024;

    // phase 0: zero degree counters
    for (int i = gt; i < n; i += GT) deg[i] = 0;
    grid.sync();

    // phase 1: histogram of dst
    for (int e = gt; e < E; e += GT) atomicAdd(&deg[ei[E + e]], 1);
    grid.sync();

    // phase 2: per-tile exclusive scan (block b owns tile b); rowptr holds tile-local excl
    __shared__ int ws[16];
    const int gi = gt;
    int v = (gi < n) ? deg[gi] : 0;
    int lane = t & 63, w = t >> 6;
    int s = v;
#pragma unroll
    for (int off = 1; off < 64; off <<= 1) {
        int u = __shfl_up(s, off);
        if (lane >= off) s += u;
    }
    if (lane == 63) ws[w] = s;
    __syncthreads();
    if (w == 0) {
        int x = (lane < 16) ? ws[lane] : 0;
#pragma unroll
        for (int off = 1; off < 16; off <<= 1) {
            int u = __shfl_up(x, off);
            if (lane >= off) x += u;
        }
        if (lane < 16) ws[lane] = x;
    }
    __syncthreads();
    int woff = (w > 0) ? ws[w - 1] : 0;
    if (gi < n) rowptr[gi] = woff + s - v;
    if (t == 1023) bsum[b] = woff + s;
    grid.sync();

    // phase 3: add cross-tile offsets
    __shared__ int sboff;
    if (t < 64) {
        int vv = (t < (int)gridDim.x) ? bsum[t] : 0;
        int ss = vv;
#pragma unroll
        for (int off = 1; off < 64; off <<= 1) {
            int u = __shfl_up(ss, off);
            if (t >= off) ss += u;
        }
        if (t == b) sboff = ss - vv;
    }
    __syncthreads();
    if (gi < n) {
        int r = rowptr[gi] + sboff;
        rowptr[gi] = r;
        cursor[gi] = r;
        if (gi == n - 1) rowptr[n] = r + deg[gi];
    }
    grid.sync();

    // phase 4: scatter src ids into CSR order
    for (int e = gt; e < E; e += GT) {
        int d = ei[E + e];
        int pos = atomicAdd(&cursor[d], 1);
        adj[pos] = ei[e];
    }
}

// ---------------- bf16 MFMA GEMM + fused attention partial dots ----------------
// C[n x 256] = A @ W^T (bf16 out). Block (bx,by) stores per-row partial dots
// (cross-wave reduced in LDS): a_part[by*N + row] (L half), a_part[2N + by*N + row] (R half).
// BM=128, BN=128, BK=32, 256 threads = 4 waves (2x2), each wave 64x64 out.
__global__ __launch_bounds__(256) void gemm_bf16(const ushort_t* __restrict__ A,
        const ushort_t* __restrict__ B, ushort_t* __restrict__ C,
        const float* __restrict__ att, float* __restrict__ a_part, int n) {
    __shared__ ushort_t As[128 * 32];
    __shared__ ushort_t Bs[128 * 32];
    __shared__ float redL[2][128];   // [wc][row_local]
    __shared__ float redR[2][128];
    const int t = threadIdx.x;
    const int lane = t & 63, wid = t >> 6;
    const int wr = wid >> 1, wc = wid & 1;
    const long brow = (long)blockIdx.x * 128;
    const int bcol = blockIdx.y * 128;

    f32x4 acc[4][4] = {};

    const int r0 = wid * 16 + (lane >> 2);
    const int kof = (lane & 3) * 8;
    const int fr = lane & 15, kg = lane >> 4;

    for (int kt = 0; kt < 256; kt += 32) {
        __builtin_amdgcn_global_load_lds(
            (const __attribute__((address_space(1))) void*)(A + (brow + r0) * 256 + kt + kof),
            (__attribute__((address_space(3))) void*)(As + wid * 512 + lane * 8), 16, 0, 0);
        __builtin_amdgcn_global_load_lds(
            (const __attribute__((address_space(1))) void*)(A + (brow + r0 + 64) * 256 + kt + kof),
            (__attribute__((address_space(3))) void*)(As + (wid + 4) * 512 + lane * 8), 16, 0, 0);
        __builtin_amdgcn_global_load_lds(
            (const __attribute__((address_space(1))) void*)(B + (bcol + r0) * 256 + kt + kof),
            (__attribute__((address_space(3))) void*)(Bs + wid * 512 + lane * 8), 16, 0, 0);
        __builtin_amdgcn_global_load_lds(
            (const __attribute__((address_space(1))) void*)(B + (bcol + r0 + 64) * 256 + kt + kof),
            (__attribute__((address_space(3))) void*)(Bs + (wid + 4) * 512 + lane * 8), 16, 0, 0);
        asm volatile("s_waitcnt vmcnt(0)" ::: "memory");
        __syncthreads();

        s16x8 a[4], b[4];
#pragma unroll
        for (int m = 0; m < 4; m++)
            a[m] = *(const s16x8*)(As + (wr * 64 + m * 16 + fr) * 32 + kg * 8);
#pragma unroll
        for (int nn = 0; nn < 4; nn++)
            b[nn] = *(const s16x8*)(Bs + (wc * 64 + nn * 16 + fr) * 32 + kg * 8);
#pragma unroll
        for (int m = 0; m < 4; m++)
#pragma unroll
            for (int nn = 0; nn < 4; nn++)
                acc[m][nn] = __builtin_amdgcn_mfma_f32_16x16x32_bf16(a[m], b[nn], acc[m][nn], 0, 0, 0);
        __syncthreads();
    }

    const int rg = lane >> 4;
    const float* attL = att;
    const float* attR = att + 256;
#pragma unroll
    for (int m = 0; m < 4; m++) {
        long rbase = brow + wr * 64 + m * 16 + rg * 4;
#pragma unroll
        for (int r = 0; r < 4; r++) {
            long row = rbase + r;
            float sL = 0.f, sR = 0.f;
#pragma unroll
            for (int nn = 0; nn < 4; nn++) {
                int col = bcol + wc * 64 + nn * 16 + fr;
                float v = acc[m][nn][r];
                C[row * 256 + col] = f2bf(v);
                sL = fmaf(v, attL[col], sL);
                sR = fmaf(v, attR[col], sR);
            }
            // reduce across the 16 fr-lanes of this rg group
#pragma unroll
            for (int off = 8; off; off >>= 1) {
                sL += __shfl_xor(sL, off);
                sR += __shfl_xor(sR, off);
            }
            if (fr == 0) {
                int rl = wr * 64 + m * 16 + rg * 4 + r;
                redL[wc][rl] = sL;   // disjoint [wc][rl] slots across the 4 waves
                redR[wc][rl] = sR;
            }
        }
    }
    __syncthreads();
    // combine the two column-strip partials (wc=0: cols 0-63, wc=1: cols 64-127 of this by)
    if (t < 128) {
        long row = brow + t;
        if (row < n) {
            float* aL = a_part + (size_t)blockIdx.y * n;
            float* aR = a_part + 2 * (size_t)n + (size_t)blockIdx.y * n;
            aL[row] = redL[0][t] + redL[1][t];
            aR[row] = redR[0][t] + redR[1][t];
        }
    }
}

// ---------------- fused segment-softmax + weighted aggregation ----------------
// a_dst(node) = aL0+aL1, a_src(node) = aR0+aR1 (partial slots from gemm).
__global__ __launch_bounds__(256) void gat_agg(const ushort_t* __restrict__ H,
        const float* __restrict__ a_part,
        const int* __restrict__ rowptr, const int* __restrict__ adj,
        const float* __restrict__ bias, ushort_t* __restrict__ OUTbf, int n) {
    int w = threadIdx.x >> 6, lane = threadIdx.x & 63;
    int node = blockIdx.x * 4 + w;
    if (node >= n) return;
    int beg = rowptr[node], end = rowptr[node + 1];
    int degree = end - beg;
    const float* aL0 = a_part;
    const float* aL1 = a_part + n;
    const float* aR0 = a_part + 2 * (size_t)n;
    const float* aR1 = a_part + 3 * (size_t)n;
    float ai = aL0[node] + aL1[node];

    const int g = lane >> 4, fl = lane & 15;
    float ssum = 0.f;
    float acc[16];
#pragma unroll
    for (int k = 0; k < 16; k++) acc[k] = 0.f;
    float m;

    if (degree <= 64) {
        // pass 1: lane j caches edge beg+j
        int sidx_c = 0;
        float e_c = -3.4e38f;
        if (lane < degree) {
            sidx_c = adj[beg + lane];
            float tt = ai + aR0[sidx_c] + aR1[sidx_c];
            e_c = (tt > 0.f) ? tt : NEG_SLOPE * tt;
        }
        m = e_c;
#pragma unroll
        for (int off = 32; off; off >>= 1) m = fmaxf(m, __shfl_xor(m, off));

        // pass 2 via shfl broadcast: group g handles edge j0+g, lane fl covers 16 feats
        for (int j0 = 0; j0 < degree; j0 += 4) {
            int j = j0 + g;
            if (j < degree) {
                float ej = __shfl(e_c, j);
                int sj = __shfl(sidx_c, j);
                float wgt = expf(ej - m);
                ssum += wgt;
                const ushort_t* hp = H + (size_t)sj * 256 + fl * 16;
                uint4 q0 = *(const uint4*)(hp);
                uint4 q1 = *(const uint4*)(hp + 8);
                uint_t qs[8] = {q0.x, q0.y, q0.z, q0.w, q1.x, q1.y, q1.z, q1.w};
#pragma unroll
                for (int k = 0; k < 8; k++) {
                    float flo = __uint_as_float(qs[k] << 16);
                    float fhi = __uint_as_float(qs[k] & 0xffff0000u);
                    acc[2 * k]     = fmaf(wgt, flo, acc[2 * k]);
                    acc[2 * k + 1] = fmaf(wgt, fhi, acc[2 * k + 1]);
                }
            }
        }
    } else {
        // generic fallback
        m = -3.4e38f;
        for (int j = beg + lane; j < end; j += 64) {
            int s = adj[j];
            float e = ai + aR0[s] + aR1[s];
            e = (e > 0.f) ? e : NEG_SLOPE * e;
            m = fmaxf(m, e);
        }
#pragma unroll
        for (int off = 32; off; off >>= 1) m = fmaxf(m, __shfl_xor(m, off));

        for (int j0 = beg; j0 < end; j0 += 4) {
            int j = j0 + g;
            if (j < end) {
                int sidx = adj[j];
                float tt = ai + aR0[sidx] + aR1[sidx];
                tt = (tt > 0.f) ? tt : NEG_SLOPE * tt;
                float wgt = expf(tt - m);
                ssum += wgt;
                const ushort_t* hp = H + (size_t)sidx * 256 + fl * 16;
                uint4 q0 = *(const uint4*)(hp);
                uint4 q1 = *(const uint4*)(hp + 8);
                uint_t qs[8] = {q0.x, q0.y, q0.z, q0.w, q1.x, q1.y, q1.z, q1.w};
#pragma unroll
                for (int k = 0; k < 8; k++) {
                    float flo = __uint_as_float(qs[k] << 16);
                    float fhi = __uint_as_float(qs[k] & 0xffff0000u);
                    acc[2 * k]     = fmaf(wgt, flo, acc[2 * k]);
                    acc[2 * k + 1] = fmaf(wgt, fhi, acc[2 * k + 1]);
                }
            }
        }
    }

    // cross-group reduce (groups differ in lane bits 4,5)
#pragma unroll
    for (int k = 0; k < 16; k++) {
        acc[k] += __shfl_xor(acc[k], 16);
        acc[k] += __shfl_xor(acc[k], 32);
    }
    ssum += __shfl_xor(ssum, 16);
    ssum += __shfl_xor(ssum, 32);

    if (g == 0) {
        float inv = 1.f / (ssum + 1e-16f);
        float bv[16];
        *(float4*)&bv[0]  = *(const float4*)(bias + fl * 16);
        *(float4*)&bv[4]  = *(const float4*)(bias + fl * 16 + 4);
        *(float4*)&bv[8]  = *(const float4*)(bias + fl * 16 + 8);
        *(float4*)&bv[12] = *(const float4*)(bias + fl * 16 + 12);
        uint_t ou[8];
#pragma unroll
        for (int k = 0; k < 8; k++) {
            uint_t lo = f2bf(acc[2 * k] * inv + bv[2 * k]);
            uint_t hi = f2bf(acc[2 * k + 1] * inv + bv[2 * k + 1]);
            ou[k] = lo | (hi << 16);
        }
        uint4* op = (uint4*)(OUTbf + (size_t)node * 256 + fl * 16);
        op[0] = make_uint4(ou[0], ou[1], ou[2], ou[3]);
        op[1] = make_uint4(ou[4], ou[5], ou[6], ou[7]);
    }
}

// ---------------- fused relu + global max pool + post-MLP + log_softmax ----------------
// One block per graph: 1024 threads pool (4-row groups), then 256-thread MLP.
__global__ __launch_bounds__(1024) void poolfinal_kernel(const ushort_t* __restrict__ X,
        const int* __restrict__ batch,
        const float* __restrict__ pW1, const float* __restrict__ pb1,
        const float* __restrict__ pW2, const float* __restrict__ pb2,
        float* __restrict__ out, int n) {
    __shared__ float red[4][256];
    __shared__ float gl[256];
    __shared__ float h1[256];
    int g = blockIdx.x;
    int t = threadIdx.x;
    int c = t & 255;
    int rg = t >> 8;
    int lo = 0, hi = n;
    while (lo < hi) { int mid = (lo + hi) >> 1; if (batch[mid] < g) lo = mid + 1; else hi = mid; }
    int start = lo;
    hi = n;
    while (lo < hi) { int mid = (lo + hi) >> 1; if (batch[mid] < g + 1) lo = mid + 1; else hi = mid; }
    int end_ = lo;
    float m = 0.f;  // relu floor
    for (int i = start + rg; i < end_; i += 4)
        m = fmaxf(m, bf2f(X[(size_t)i * 256 + c]));
    red[rg][c] = m;
    __syncthreads();
    if (rg == 0)
        gl[c] = fmaxf(fmaxf(red[0][c], red[1][c]), fmaxf(red[2][c], red[3][c]));
    __syncthreads();
    if (t < 256) {
        float acc = pb1[t];
        for (int k = 0; k < 256; k++) acc = fmaf(gl[k], pW1[t * 256 + k], acc);
        h1[t] = acc;
    }
    __syncthreads();
    if (t < 64) {
        float o = pb2[t];
        for (int k = 0; k < 256; k++) o = fmaf(h1[k], pW2[t * 256 + k], o);
        float mx = o;
#pragma unroll
        for (int off = 32; off; off >>= 1) mx = fmaxf(mx, __shfl_xor(mx, off));
        float ex = expf(o - mx);
        float s = ex;
#pragma unroll
        for (int off = 32; off; off >>= 1) s += __shfl_xor(s, off);
        out[g * 64 + t] = o - mx - logf(s);
    }
}

extern "C" void kernel_launch(void* const* d_in, const int* in_sizes, int n_in,
                              void* d_out, int out_size, void* d_ws, size_t ws_size,
                              hipStream_t stream) {
    const float* x     = (const float*)d_in[0];
    const int*   ei    = (const int*)d_in[1];
    const int*   batch = (const int*)d_in[2];
    const float* Ws    = (const float*)d_in[3];
    const float* atts  = (const float*)d_in[4];
    const float* bs    = (const float*)d_in[5];
    const float* pW1   = (const float*)d_in[6];
    const float* pb1   = (const float*)d_in[7];
    const float* pW2   = (const float*)d_in[8];
    const float* pb2   = (const float*)d_in[9];
    float* out = (float*)d_out;

    const int N = in_sizes[0] / 256;
    const int E = in_sizes[1] / 2;
    const int G = out_size / 64;
    const int L = in_sizes[3] / (256 * 256);
    const int MB = (N + 127) / 128;       // row blocks
    const int Npad = MB * 128;
    const int NT = (N + 1023) / 1024;     // scan tiles

    char* ws = (char*)d_ws;
    size_t off = 0;
    auto alloc = [&](size_t bytes) -> char* {
        char* p = ws + off;
        off += (bytes + 255) & ~size_t(255);
        return p;
    };
    ushort_t* Hbf    = (ushort_t*)alloc((size_t)Npad * 256 * 2);
    ushort_t* Xbf    = (ushort_t*)alloc((size_t)Npad * 256 * 2);
    ushort_t* Wbf    = (ushort_t*)alloc((size_t)L * 256 * 256 * 2);
    float*    a_part = (float*)alloc((size_t)4 * N * 4);   // [L0|L1|R0|R1], reused per layer
    int*      deg    = (int*)alloc((size_t)N * 4);
    int*      rowptr = (int*)alloc((size_t)(N + 1) * 4);
    int*      cursor = (int*)alloc((size_t)N * 4);
    int*      adj    = (int*)alloc((size_t)E * 4);
    int*      bsum   = (int*)alloc((size_t)64 * 4);

    // cooperative CSR build: zero + histogram + scan + scatter, one dispatch
    {
        int E_ = E, N_ = N;
        const int* ei_ = ei;
        int *deg_ = deg, *rowptr_ = rowptr, *cursor_ = cursor, *adj_ = adj, *bsum_ = bsum;
        void* cargs[] = {(void*)&ei_, (void*)&deg_, (void*)&rowptr_, (void*)&cursor_,
                         (void*)&adj_, (void*)&bsum_, (void*)&E_, (void*)&N_};
        hipLaunchCooperativeKernel((const void*)csr_coop, dim3(NT), dim3(1024),
                                   cargs, 0, stream);
    }

    // bf16 conversions (x and Ws in one launch)
    int na4 = N * 64, nb4 = L * 16384;
    cvt2_kernel<<<(na4 + nb4 + 255) / 256, 256, 0, stream>>>(x, Xbf, na4, Ws, Wbf, nb4);

    for (int l = 0; l < L; ++l) {
        dim3 ggrid(MB, 2);
        gemm_bf16<<<ggrid, 256, 0, stream>>>(Xbf, Wbf + (size_t)l * 65536, Hbf,
                                             atts + (size_t)l * 512, a_part, N);
        gat_agg<<<(N + 3) / 4, 256, 0, stream>>>(Hbf, a_part, rowptr, adj,
                                                 bs + (size_t)l * 256, Xbf, N);
    }
    poolfinal_kernel<<<G, 1024, 0, stream>>>(Xbf, batch, pW1, pb1, pW2, pb2, out, N);
}